// Round 12
// baseline (1302.391 us; speedup 1.0000x reference)
//
#include <hip/hip_runtime.h>
#include <hip/hip_bf16.h>
#include <math.h>

#define SEQ   2048
#define BATCH 32
#define DIM   1024
#define MROWS (SEQ*BATCH)   // 65536 rows, r = s*32 + b
#define NT2   4             // 1024 / 256 N-tiles
#define NCH   16            // context s-chunks (x2 sub-chunks inside kernel)
#define NKT   32            // K-tiles of 32

typedef __attribute__((ext_vector_type(8))) short short8;
typedef __attribute__((ext_vector_type(8))) unsigned short u16x8;
typedef __attribute__((ext_vector_type(4))) float f32x4;

__device__ __forceinline__ unsigned short f2bf(float f) {
  unsigned u = __builtin_bit_cast(unsigned, f);
  u += 0x7FFFu + ((u >> 16) & 1u);      // round-to-nearest-even
  return (unsigned short)(u >> 16);
}

// async global -> LDS, 16 B per lane (dest = wave-uniform base + lane*16)
__device__ __forceinline__ void gl16(const unsigned short* g, unsigned short* l) {
  __builtin_amdgcn_global_load_lds(
      (const __attribute__((address_space(1))) unsigned int*)g,
      (__attribute__((address_space(3))) unsigned int*)l, 16, 0, 0);
}

// ---------------- fp32 -> bf16 bulk convert ----------------
__global__ __launch_bounds__(256) void conv_bf16_k(const float* __restrict__ src,
                                                   unsigned short* __restrict__ dst) {
  size_t i = ((size_t)blockIdx.x * 256 + threadIdx.x) * 8;
  f32x4 a = __builtin_nontemporal_load(reinterpret_cast<const f32x4*>(src + i));
  f32x4 b = __builtin_nontemporal_load(reinterpret_cast<const f32x4*>(src + i + 4));
  u16x8 o;
  o[0] = f2bf(a[0]); o[1] = f2bf(a[1]); o[2] = f2bf(a[2]); o[3] = f2bf(a[3]);
  o[4] = f2bf(b[0]); o[5] = f2bf(b[1]); o[6] = f2bf(b[2]); o[7] = f2bf(b[3]);
  *reinterpret_cast<u16x8*>(dst + i) = o;
}

// ---------------- q[b,e] = sum_d dh[b,d] * W_dec[e,d] ----------------
__global__ __launch_bounds__(256) void qpart_k(const float* __restrict__ dh,
                                               const float* __restrict__ Wd,
                                               float* __restrict__ qpart) {
  const int bx = blockIdx.x;        // 32 blocks
  const int eb = bx & 3;            // 4 e-blocks of 256
  const int dc = bx >> 2;           // 8 d-chunks of 128
  __shared__ float ldh[BATCH][128];
  const int tid = threadIdx.x;
#pragma unroll
  for (int i = 0; i < 4; ++i) {
    int idx = tid + i * 256;
    int bb = idx >> 5, d4 = idx & 31;
    float4 v = *reinterpret_cast<const float4*>(&dh[(size_t)bb * DIM + dc * 128 + d4 * 4]);
    *reinterpret_cast<float4*>(&ldh[bb][d4 * 4]) = v;
  }
  __syncthreads();
  const int e = eb * 256 + tid;
  float acc[BATCH];
#pragma unroll
  for (int b = 0; b < BATCH; ++b) acc[b] = 0.f;
  for (int d4 = 0; d4 < 32; ++d4) {
    float4 w = *reinterpret_cast<const float4*>(&Wd[(size_t)e * DIM + dc * 128 + d4 * 4]);
#pragma unroll
    for (int b = 0; b < BATCH; ++b) {
      float4 h = *reinterpret_cast<const float4*>(&ldh[b][d4 * 4]);
      acc[b] += w.x * h.x + w.y * h.y + w.z * h.z + w.w * h.w;
    }
  }
#pragma unroll
  for (int b = 0; b < BATCH; ++b)
    qpart[((size_t)dc * BATCH + b) * DIM + e] = acc[b];
}

__global__ __launch_bounds__(256) void qred_k(const float* __restrict__ qpart,
                                              float* __restrict__ q) {
  int i = blockIdx.x * 256 + threadIdx.x;
  float s = 0.f;
#pragma unroll
  for (int dc = 0; dc < 8; ++dc) s += qpart[(size_t)dc * 32768 + i];
  q[i] = s;
}

// ============ 256^2 4-phase fused GEMM, BK=32, 64KB LDS -> 2 blocks/CU ============
// R11 4-phase skeleton (neutral-verified vs champion) with all pieces halved:
// piece = 128 rows x 32 K x 2B = 8KB = ONE gl16. Arena 64KB -> 2 blocks/CU
// (VGPR=128 exactly fits 16 waves/CU). Same K-ascending MFMA order as champion
// -> bit-identical output. Swizzle: lc = kq ^ ((row>>1)&3) on 4-chunk rows
// (row&1 is the bank-half bit; uniform 8 lanes/bank-group, conflict-free).
// FIFO ledger (1 gl16/piece): enter iter with 2 outstanding (t2+1.h0);
// P1 +2 (t2+1.h1); P2 +2 (t2+2.h0), VMC(2) drains t2+1 fully; P3 +2 (t2+2.h1);
// P4 +2 (t2+3.h0), VMC(2) drains t2+2 fully. Last iter: P2 -> VMC(0), P3/P4
// stages+VMC suppressed. WAR: every stage >=1 barrier after its region's reads
// were consumed (audited per piece).
#define BARR  __builtin_amdgcn_s_barrier()
#define VMC(n) asm volatile("s_waitcnt vmcnt(" #n ")" ::: "memory")

#define STAGE_A(t, h) do {                                                        \
    gl16(Abase + (size_t)(gAr + (h) * 64) * 1024 + (t) * 32 + cSt * 8,            \
         (unsigned short*)(arena + (((t) & 1) * 32768) + (h) * 8192) + w * 512);  \
  } while (0)

#define STAGE_B(t, h) do {                                                        \
    gl16(Bbase + (size_t)(gBr + (h) * 32) * 1024 + (t) * 32 + cSt * 8,            \
         (unsigned short*)(arena + (((t) & 1) * 32768) + 16384 + (h) * 8192)      \
             + w * 512);                                                          \
  } while (0)

#define LOAD_A(d, MH) do {                                                        \
    const char* bA_ = arena + (d) * 32768 + (MH) * 8192;                          \
    _Pragma("unroll") for (int i_ = 0; i_ < 4; ++i_) {                            \
      int lrow_ = wr * 64 + i_ * 16 + fr;                                         \
      int lc_ = kq ^ ((lrow_ >> 1) & 3);                                          \
      a[i_] = *(const short8*)(bA_ + lrow_ * 64 + lc_ * 16);                      \
    } } while (0)

#define LOAD_B(SET, d, NH) do {                                                   \
    const char* bB_ = arena + (d) * 32768 + 16384 + (NH) * 8192;                  \
    _Pragma("unroll") for (int j_ = 0; j_ < 2; ++j_) {                            \
      int lrow_ = wc * 32 + j_ * 16 + fr;                                         \
      int lc_ = kq ^ ((lrow_ >> 1) & 3);                                          \
      SET[j_] = *(const short8*)(bB_ + lrow_ * 64 + lc_ * 16);                    \
    } } while (0)

#define QUAD(BSET, MH, NH) do {                                                   \
    __builtin_amdgcn_s_setprio(1);                                                \
    _Pragma("unroll") for (int i_ = 0; i_ < 4; ++i_)                              \
    _Pragma("unroll") for (int j_ = 0; j_ < 2; ++j_)                              \
      acc[(MH) * 4 + i_][(NH) * 2 + j_] =                                         \
          __builtin_amdgcn_mfma_f32_16x16x32_bf16(                                \
              a[i_], BSET[j_], acc[(MH) * 4 + i_][(NH) * 2 + j_], 0, 0, 0);       \
    __builtin_amdgcn_s_setprio(0);                                                \
  } while (0)

__global__ __launch_bounds__(512, 4) void gemm8p(const unsigned short* __restrict__ A,
                                                 const unsigned short* __restrict__ B,
                                                 const float* __restrict__ q,
                                                 const float* __restrict__ V,
                                                 float* __restrict__ lpart) {
  __shared__ __align__(16) char arena[65536];    // 2 bufs x (A 16KB | B 16KB)

  const int bid = blockIdx.x;
  const int wg = (bid & 7) * 128 + (bid >> 3);   // XCD-bijective (1024 % 8 == 0)
  const int mt = wg >> 2, nt = wg & 3;
  const int row0 = mt * 256, col0 = nt * 256;
  const int tid = threadIdx.x;
  const int lane = tid & 63, w = tid >> 6;
  const int wr = w >> 2, wc = w & 3;             // 2 x 4 waves, each 128x64 out
  const int fr = lane & 15, kq = lane >> 4;

  // stage lane geometry: slot u covers piece row lr = u>>2 (4 chunks/row);
  // LDS chunk (u&3) holds global chunk (u&3)^((lr>>1)&3)  [involution with read]
  const int lr0 = tid >> 2;                      // 0..127
  const int cSt = (tid & 3) ^ ((lr0 >> 1) & 3);
  const int gAr = (lr0 & 63) + (lr0 >> 6) * 128; // A piece h: global row gAr + h*64
  const int gBr = (lr0 & 31) + (lr0 >> 5) * 64;  // B piece h: global row gBr + h*32

  const unsigned short* Abase = A + (size_t)row0 * DIM;
  const unsigned short* Bbase = B + (size_t)col0 * DIM;

  f32x4 acc[8][4];
#pragma unroll
  for (int i = 0; i < 8; ++i)
#pragma unroll
    for (int j = 0; j < 4; ++j) acc[i][j] = (f32x4)(0.f);

  short8 a[4];           // current A-half fragments (reloaded each phase)
  short8 b0[2], b1[2];   // N0 / N1 fragment sets (reloaded per K-tile)

  // ---- prologue: tile0 full + tile1 h0; VMC(2) leaves t1.h0 in flight ----
  STAGE_A(0, 0); STAGE_B(0, 0); STAGE_A(0, 1); STAGE_B(0, 1);
  STAGE_A(1, 0); STAGE_B(1, 0);
  VMC(2);
  BARR;

#pragma unroll 1
  for (int t2 = 0; t2 < NKT; t2 += 2) {
    const bool last = (t2 == NKT - 2);
    // P1: tile t2 (buf0), quads (M0,N0)+(M0,N1)
    LOAD_A(0, 0); LOAD_B(b0, 0, 0); LOAD_B(b1, 0, 1);
    STAGE_A(t2 + 1, 1); STAGE_B(t2 + 1, 1);
    BARR; QUAD(b0, 0, 0); QUAD(b1, 0, 1); BARR;
    // P2: quads (M1,N0)+(M1,N1); gate buf1 (tile t2+1)
    LOAD_A(0, 1);
    if (!last) { STAGE_A(t2 + 2, 0); STAGE_B(t2 + 2, 0); VMC(2); } else { VMC(0); }
    BARR; QUAD(b0, 1, 0); QUAD(b1, 1, 1); BARR;
    // P3: tile t2+1 (buf1), quads (M0,N0)+(M0,N1)
    LOAD_A(1, 0); LOAD_B(b0, 1, 0); LOAD_B(b1, 1, 1);
    if (!last) { STAGE_A(t2 + 2, 1); STAGE_B(t2 + 2, 1); }
    BARR; QUAD(b0, 0, 0); QUAD(b1, 0, 1); BARR;
    // P4: quads (M1,N0)+(M1,N1); gate next buf0 (tile t2+2)
    LOAD_A(1, 1);
    if (!last) { STAGE_A(t2 + 3, 0); STAGE_B(t2 + 3, 0); VMC(2); }
    BARR; QUAD(b0, 1, 0); QUAD(b1, 1, 1); BARR;
  }

  // ================= epilogue =================
  __syncthreads();                 // staging LDS dead; overlay q/V/red
  float* qld = (float*)arena;                    // [32][260] padded
  float* vld = (float*)(arena + 33280);          // [256]
  float* red = (float*)(arena + 34304);          // [4][256]
#pragma unroll
  for (int i = 0; i < 4; ++i) {
    int id = i * 512 + tid;                      // 2048 float4s
    int bb = id >> 6, e4 = id & 63;
    float4 v = *(const float4*)&q[(size_t)bb * DIM + col0 + e4 * 4];
    *(float4*)&qld[bb * 260 + e4 * 4] = v;
  }
  if (tid < 64) *(float4*)&vld[tid * 4] = *(const float4*)&V[col0 + tid * 4];
  __syncthreads();

#pragma unroll
  for (int mf = 0; mf < 8; ++mf) {
#pragma unroll
    for (int reg = 0; reg < 4; ++reg) {
      const int m_loc = wr * 128 + mf * 16 + kq * 4 + reg;
      const int bb = m_loc & 31;                 // row0 % 32 == 0
      float val = 0.f;
#pragma unroll
      for (int nf = 0; nf < 4; ++nf) {
        const int el = wc * 64 + nf * 16 + fr;
        float x = acc[mf][nf][reg] + qld[bb * 260 + el];
        float g = __expf(2.f * x);
        float tnh = 1.f - 2.f * __builtin_amdgcn_rcpf(g + 1.f);
        val += tnh * vld[el];
      }
      val += __shfl_xor(val, 1); val += __shfl_xor(val, 2);
      val += __shfl_xor(val, 4); val += __shfl_xor(val, 8);
      if (fr == 0) red[wc * 256 + m_loc] = val;
    }
  }
  __syncthreads();
  if (tid < 256) {
    float s = red[tid] + red[256 + tid] + red[512 + tid] + red[768 + tid];
    lpart[(size_t)(row0 + tid) * NT2 + nt] = s;
  }
}

// ---------------- softmax over seq per batch ----------------
__global__ __launch_bounds__(256) void softmax_k(const float* __restrict__ lpart,
                                                 float* __restrict__ alpha) {
  const int b = blockIdx.x;
  __shared__ float lv[SEQ];
  __shared__ float sred[4];
  const int tid = threadIdx.x;
  float mx = -1e30f;
  for (int s = tid; s < SEQ; s += 256) {
    const float* p = &lpart[(size_t)(s * BATCH + b) * NT2];
    float v = p[0] + p[1] + p[2] + p[3];
    lv[s] = v;
    mx = fmaxf(mx, v);
  }
#pragma unroll
  for (int off = 32; off >= 1; off >>= 1) mx = fmaxf(mx, __shfl_xor(mx, off));
  if ((tid & 63) == 0) sred[tid >> 6] = mx;
  __syncthreads();
  mx = fmaxf(fmaxf(sred[0], sred[1]), fmaxf(sred[2], sred[3]));
  __syncthreads();
  float sm = 0.f;
  for (int s = tid; s < SEQ; s += 256) {
    float e = expf(lv[s] - mx);
    lv[s] = e;
    sm += e;
  }
#pragma unroll
  for (int off = 32; off >= 1; off >>= 1) sm += __shfl_xor(sm, off);
  if ((tid & 63) == 0) sred[tid >> 6] = sm;
  __syncthreads();
  const float inv = 1.f / (sred[0] + sred[1] + sred[2] + sred[3]);
  for (int s = tid; s < SEQ; s += 256)
    alpha[(size_t)b * SEQ + s] = lv[s] * inv;
}

// ---------------- context partials from bf16 enc copy ----------------
__global__ __launch_bounds__(256) void ctx_part_k(const unsigned short* __restrict__ encbf,
                                                  const float* __restrict__ alpha,
                                                  float* __restrict__ cpart) {
  const int blk = blockIdx.x;                   // 512 blocks
  const int b = blk & 31;
  const int ch = blk >> 5;                      // 0..15
  const int tid = threadIdx.x;
  const int g = tid >> 7;                       // 0/1 sub-chunk
  const int d0 = (tid & 127) * 8;
  const int s0 = ch * (SEQ / NCH);
  float acc8[8];
#pragma unroll
  for (int k = 0; k < 8; ++k) acc8[k] = 0.f;
#pragma unroll 4
  for (int i = 0; i < SEQ / NCH; i += 2) {
    const int s = s0 + i + g;
    const float a = alpha[(size_t)b * SEQ + s];
    u16x8 v = *reinterpret_cast<const u16x8*>(&encbf[((size_t)s * BATCH + b) * DIM + d0]);
#pragma unroll
    for (int k = 0; k < 8; ++k) {
      float f = __builtin_bit_cast(float, (unsigned)v[k] << 16);
      acc8[k] += a * f;
    }
  }
  size_t o = ((size_t)(ch * 2 + g) * BATCH + b) * DIM + d0;
  float4 lo = {acc8[0], acc8[1], acc8[2], acc8[3]};
  float4 hi = {acc8[4], acc8[5], acc8[6], acc8[7]};
  *(float4*)&cpart[o] = lo;
  *(float4*)&cpart[o + 4] = hi;
}

__global__ __launch_bounds__(256) void ctxred_k(const float* __restrict__ cpart,
                                                float* __restrict__ out) {
  int i = blockIdx.x * 256 + threadIdx.x;
  float s = 0.f;
#pragma unroll
  for (int ch = 0; ch < 32; ++ch) s += cpart[(size_t)ch * 32768 + i];
  out[i] = s;
}

extern "C" void kernel_launch(void* const* d_in, const int* in_sizes, int n_in,
                              void* d_out, int out_size, void* d_ws, size_t ws_size,
                              hipStream_t stream) {
  const float* dh   = (const float*)d_in[0];   // (32,1,1024)
  const float* enc  = (const float*)d_in[1];   // (2048,32,1024)
  const float* Wenc = (const float*)d_in[2];   // (1024,1024)
  const float* Wdec = (const float*)d_in[3];   // (1024,1024)
  const float* Vatt = (const float*)d_in[4];   // (1,1024)
  float* out = (float*)d_out;                  // [0,32768) context, [32768,98304) alpha

  float* ws = (float*)d_ws;
  float* q      = ws;                                   // 32768
  float* qpart  = ws + 32768;                           // 262144
  float* lpart  = ws + 294912;                          // 262144
  float* cpart  = ws + 557056;                          // 32*32768 = 1048576
  unsigned short* Wbf   = (unsigned short*)(ws + 1605632);  // 1Mi bf16
  unsigned short* encbf = (unsigned short*)(ws + 2129920);  // 64Mi bf16

  conv_bf16_k<<<dim3(512),   dim3(256), 0, stream>>>(Wenc, Wbf);
  qpart_k    <<<dim3(32),    dim3(256), 0, stream>>>(dh, Wdec, qpart);
  qred_k     <<<dim3(128),   dim3(256), 0, stream>>>(qpart, q);
  conv_bf16_k<<<dim3(32768), dim3(256), 0, stream>>>(enc, encbf);
  gemm8p     <<<dim3(1024),  dim3(512), 0, stream>>>(encbf, Wbf, q, Vatt, lpart);
  softmax_k  <<<dim3(BATCH),     dim3(256), 0, stream>>>(lpart, out + 32768);
  ctx_part_k <<<dim3(BATCH*NCH), dim3(256), 0, stream>>>(encbf, out + 32768, cpart);
  ctxred_k   <<<dim3(128),       dim3(256), 0, stream>>>(cpart, out);
}

// Round 13
// 280.921 us; speedup vs baseline: 4.6361x; 4.6361x over previous
//
#include <hip/hip_runtime.h>
#include <hip/hip_bf16.h>
#include <math.h>

#define SEQ   2048
#define BATCH 32
#define DIM   1024
#define MROWS (SEQ*BATCH)   // 65536 rows, r = s*32 + b
#define NT2   4             // 1024 / 256 N-tiles
#define NCH   16            // context s-chunks (x2 sub-chunks inside kernel)
#define NKT   32            // K-tiles of 32

typedef __attribute__((ext_vector_type(8))) short short8;
typedef __attribute__((ext_vector_type(8))) unsigned short u16x8;
typedef __attribute__((ext_vector_type(4))) float f32x4;

__device__ __forceinline__ unsigned short f2bf(float f) {
  unsigned u = __builtin_bit_cast(unsigned, f);
  u += 0x7FFFu + ((u >> 16) & 1u);      // round-to-nearest-even
  return (unsigned short)(u >> 16);
}

// async global -> LDS, 16 B per lane (dest = wave-uniform base + lane*16)
__device__ __forceinline__ void gl16(const unsigned short* g, unsigned short* l) {
  __builtin_amdgcn_global_load_lds(
      (const __attribute__((address_space(1))) unsigned int*)g,
      (__attribute__((address_space(3))) unsigned int*)l, 16, 0, 0);
}

// ---------------- fp32 -> bf16 bulk convert ----------------
__global__ __launch_bounds__(256) void conv_bf16_k(const float* __restrict__ src,
                                                   unsigned short* __restrict__ dst) {
  size_t i = ((size_t)blockIdx.x * 256 + threadIdx.x) * 8;
  f32x4 a = __builtin_nontemporal_load(reinterpret_cast<const f32x4*>(src + i));
  f32x4 b = __builtin_nontemporal_load(reinterpret_cast<const f32x4*>(src + i + 4));
  u16x8 o;
  o[0] = f2bf(a[0]); o[1] = f2bf(a[1]); o[2] = f2bf(a[2]); o[3] = f2bf(a[3]);
  o[4] = f2bf(b[0]); o[5] = f2bf(b[1]); o[6] = f2bf(b[2]); o[7] = f2bf(b[3]);
  *reinterpret_cast<u16x8*>(dst + i) = o;
}

// ---------------- q[b,e] = sum_d dh[b,d] * W_dec[e,d] ----------------
__global__ __launch_bounds__(256) void qpart_k(const float* __restrict__ dh,
                                               const float* __restrict__ Wd,
                                               float* __restrict__ qpart) {
  const int bx = blockIdx.x;        // 32 blocks
  const int eb = bx & 3;            // 4 e-blocks of 256
  const int dc = bx >> 2;           // 8 d-chunks of 128
  __shared__ float ldh[BATCH][128];
  const int tid = threadIdx.x;
#pragma unroll
  for (int i = 0; i < 4; ++i) {
    int idx = tid + i * 256;
    int bb = idx >> 5, d4 = idx & 31;
    float4 v = *reinterpret_cast<const float4*>(&dh[(size_t)bb * DIM + dc * 128 + d4 * 4]);
    *reinterpret_cast<float4*>(&ldh[bb][d4 * 4]) = v;
  }
  __syncthreads();
  const int e = eb * 256 + tid;
  float acc[BATCH];
#pragma unroll
  for (int b = 0; b < BATCH; ++b) acc[b] = 0.f;
  for (int d4 = 0; d4 < 32; ++d4) {
    float4 w = *reinterpret_cast<const float4*>(&Wd[(size_t)e * DIM + dc * 128 + d4 * 4]);
#pragma unroll
    for (int b = 0; b < BATCH; ++b) {
      float4 h = *reinterpret_cast<const float4*>(&ldh[b][d4 * 4]);
      acc[b] += w.x * h.x + w.y * h.y + w.z * h.z + w.w * h.w;
    }
  }
#pragma unroll
  for (int b = 0; b < BATCH; ++b)
    qpart[((size_t)dc * BATCH + b) * DIM + e] = acc[b];
}

__global__ __launch_bounds__(256) void qred_k(const float* __restrict__ qpart,
                                              float* __restrict__ q) {
  int i = blockIdx.x * 256 + threadIdx.x;
  float s = 0.f;
#pragma unroll
  for (int dc = 0; dc < 8; ++dc) s += qpart[(size_t)dc * 32768 + i];
  q[i] = s;
}

// ============ 256^2 4-phase fused GEMM, BK=32, 64KB LDS -> 2 blocks/CU ============
// R12 kernel verbatim EXCEPT __launch_bounds__(512, 2): min-waves=4 had capped
// the allocator at 64 VGPR -> 128-reg accumulator spilled (3GB scratch writes).
// At min-waves=2 the compiler can use <=128 VGPR (R6 needed exactly 128; BK=32
// needs fewer fragment regs), and 64KB LDS alone yields 2 blocks/CU
// (16 waves/CU at 128 VGPR = full file, m69). FIFO/WAR ledgers unchanged
// (R12 passed correctness).
#define BARR  __builtin_amdgcn_s_barrier()
#define VMC(n) asm volatile("s_waitcnt vmcnt(" #n ")" ::: "memory")

#define STAGE_A(t, h) do {                                                        \
    gl16(Abase + (size_t)(gAr + (h) * 64) * 1024 + (t) * 32 + cSt * 8,            \
         (unsigned short*)(arena + (((t) & 1) * 32768) + (h) * 8192) + w * 512);  \
  } while (0)

#define STAGE_B(t, h) do {                                                        \
    gl16(Bbase + (size_t)(gBr + (h) * 32) * 1024 + (t) * 32 + cSt * 8,            \
         (unsigned short*)(arena + (((t) & 1) * 32768) + 16384 + (h) * 8192)      \
             + w * 512);                                                          \
  } while (0)

#define LOAD_A(d, MH) do {                                                        \
    const char* bA_ = arena + (d) * 32768 + (MH) * 8192;                          \
    _Pragma("unroll") for (int i_ = 0; i_ < 4; ++i_) {                            \
      int lrow_ = wr * 64 + i_ * 16 + fr;                                         \
      int lc_ = kq ^ ((lrow_ >> 1) & 3);                                          \
      a[i_] = *(const short8*)(bA_ + lrow_ * 64 + lc_ * 16);                      \
    } } while (0)

#define LOAD_B(SET, d, NH) do {                                                   \
    const char* bB_ = arena + (d) * 32768 + 16384 + (NH) * 8192;                  \
    _Pragma("unroll") for (int j_ = 0; j_ < 2; ++j_) {                            \
      int lrow_ = wc * 32 + j_ * 16 + fr;                                         \
      int lc_ = kq ^ ((lrow_ >> 1) & 3);                                          \
      SET[j_] = *(const short8*)(bB_ + lrow_ * 64 + lc_ * 16);                    \
    } } while (0)

#define QUAD(BSET, MH, NH) do {                                                   \
    __builtin_amdgcn_s_setprio(1);                                                \
    _Pragma("unroll") for (int i_ = 0; i_ < 4; ++i_)                              \
    _Pragma("unroll") for (int j_ = 0; j_ < 2; ++j_)                              \
      acc[(MH) * 4 + i_][(NH) * 2 + j_] =                                         \
          __builtin_amdgcn_mfma_f32_16x16x32_bf16(                                \
              a[i_], BSET[j_], acc[(MH) * 4 + i_][(NH) * 2 + j_], 0, 0, 0);       \
    __builtin_amdgcn_s_setprio(0);                                                \
  } while (0)

__global__ __launch_bounds__(512, 2) void gemm8p(const unsigned short* __restrict__ A,
                                                 const unsigned short* __restrict__ B,
                                                 const float* __restrict__ q,
                                                 const float* __restrict__ V,
                                                 float* __restrict__ lpart) {
  __shared__ __align__(16) char arena[65536];    // 2 bufs x (A 16KB | B 16KB)

  const int bid = blockIdx.x;
  const int wg = (bid & 7) * 128 + (bid >> 3);   // XCD-bijective (1024 % 8 == 0)
  const int mt = wg >> 2, nt = wg & 3;
  const int row0 = mt * 256, col0 = nt * 256;
  const int tid = threadIdx.x;
  const int lane = tid & 63, w = tid >> 6;
  const int wr = w >> 2, wc = w & 3;             // 2 x 4 waves, each 128x64 out
  const int fr = lane & 15, kq = lane >> 4;

  // stage lane geometry: slot u covers piece row lr = u>>2 (4 chunks/row);
  // LDS chunk (u&3) holds global chunk (u&3)^((lr>>1)&3)  [involution with read]
  const int lr0 = tid >> 2;                      // 0..127
  const int cSt = (tid & 3) ^ ((lr0 >> 1) & 3);
  const int gAr = (lr0 & 63) + (lr0 >> 6) * 128; // A piece h: global row gAr + h*64
  const int gBr = (lr0 & 31) + (lr0 >> 5) * 64;  // B piece h: global row gBr + h*32

  const unsigned short* Abase = A + (size_t)row0 * DIM;
  const unsigned short* Bbase = B + (size_t)col0 * DIM;

  f32x4 acc[8][4];
#pragma unroll
  for (int i = 0; i < 8; ++i)
#pragma unroll
    for (int j = 0; j < 4; ++j) acc[i][j] = (f32x4)(0.f);

  short8 a[4];           // current A-half fragments (reloaded each phase)
  short8 b0[2], b1[2];   // N0 / N1 fragment sets (reloaded per K-tile)

  // ---- prologue: tile0 full + tile1 h0; VMC(2) leaves t1.h0 in flight ----
  STAGE_A(0, 0); STAGE_B(0, 0); STAGE_A(0, 1); STAGE_B(0, 1);
  STAGE_A(1, 0); STAGE_B(1, 0);
  VMC(2);
  BARR;

#pragma unroll 1
  for (int t2 = 0; t2 < NKT; t2 += 2) {
    const bool last = (t2 == NKT - 2);
    // P1: tile t2 (buf0), quads (M0,N0)+(M0,N1)
    LOAD_A(0, 0); LOAD_B(b0, 0, 0); LOAD_B(b1, 0, 1);
    STAGE_A(t2 + 1, 1); STAGE_B(t2 + 1, 1);
    BARR; QUAD(b0, 0, 0); QUAD(b1, 0, 1); BARR;
    // P2: quads (M1,N0)+(M1,N1); gate buf1 (tile t2+1)
    LOAD_A(0, 1);
    if (!last) { STAGE_A(t2 + 2, 0); STAGE_B(t2 + 2, 0); VMC(2); } else { VMC(0); }
    BARR; QUAD(b0, 1, 0); QUAD(b1, 1, 1); BARR;
    // P3: tile t2+1 (buf1), quads (M0,N0)+(M0,N1)
    LOAD_A(1, 0); LOAD_B(b0, 1, 0); LOAD_B(b1, 1, 1);
    if (!last) { STAGE_A(t2 + 2, 1); STAGE_B(t2 + 2, 1); }
    BARR; QUAD(b0, 0, 0); QUAD(b1, 0, 1); BARR;
    // P4: quads (M1,N0)+(M1,N1); gate next buf0 (tile t2+2)
    LOAD_A(1, 1);
    if (!last) { STAGE_A(t2 + 3, 0); STAGE_B(t2 + 3, 0); VMC(2); }
    BARR; QUAD(b0, 1, 0); QUAD(b1, 1, 1); BARR;
  }

  // ================= epilogue =================
  __syncthreads();                 // staging LDS dead; overlay q/V/red
  float* qld = (float*)arena;                    // [32][260] padded -> 33280 B
  float* vld = (float*)(arena + 33280);          // [256] -> 1024 B
  float* red = (float*)(arena + 34304);          // [4][256] -> 4096 B (fits 64KB)
#pragma unroll
  for (int i = 0; i < 4; ++i) {
    int id = i * 512 + tid;                      // 2048 float4s
    int bb = id >> 6, e4 = id & 63;
    float4 v = *(const float4*)&q[(size_t)bb * DIM + col0 + e4 * 4];
    *(float4*)&qld[bb * 260 + e4 * 4] = v;
  }
  if (tid < 64) *(float4*)&vld[tid * 4] = *(const float4*)&V[col0 + tid * 4];
  __syncthreads();

#pragma unroll
  for (int mf = 0; mf < 8; ++mf) {
#pragma unroll
    for (int reg = 0; reg < 4; ++reg) {
      const int m_loc = wr * 128 + mf * 16 + kq * 4 + reg;
      const int bb = m_loc & 31;                 // row0 % 32 == 0
      float val = 0.f;
#pragma unroll
      for (int nf = 0; nf < 4; ++nf) {
        const int el = wc * 64 + nf * 16 + fr;
        float x = acc[mf][nf][reg] + qld[bb * 260 + el];
        float g = __expf(2.f * x);
        float tnh = 1.f - 2.f * __builtin_amdgcn_rcpf(g + 1.f);
        val += tnh * vld[el];
      }
      val += __shfl_xor(val, 1); val += __shfl_xor(val, 2);
      val += __shfl_xor(val, 4); val += __shfl_xor(val, 8);
      if (fr == 0) red[wc * 256 + m_loc] = val;
    }
  }
  __syncthreads();
  if (tid < 256) {
    float s = red[tid] + red[256 + tid] + red[512 + tid] + red[768 + tid];
    lpart[(size_t)(row0 + tid) * NT2 + nt] = s;
  }
}

// ---------------- softmax over seq per batch ----------------
__global__ __launch_bounds__(256) void softmax_k(const float* __restrict__ lpart,
                                                 float* __restrict__ alpha) {
  const int b = blockIdx.x;
  __shared__ float lv[SEQ];
  __shared__ float sred[4];
  const int tid = threadIdx.x;
  float mx = -1e30f;
  for (int s = tid; s < SEQ; s += 256) {
    const float* p = &lpart[(size_t)(s * BATCH + b) * NT2];
    float v = p[0] + p[1] + p[2] + p[3];
    lv[s] = v;
    mx = fmaxf(mx, v);
  }
#pragma unroll
  for (int off = 32; off >= 1; off >>= 1) mx = fmaxf(mx, __shfl_xor(mx, off));
  if ((tid & 63) == 0) sred[tid >> 6] = mx;
  __syncthreads();
  mx = fmaxf(fmaxf(sred[0], sred[1]), fmaxf(sred[2], sred[3]));
  __syncthreads();
  float sm = 0.f;
  for (int s = tid; s < SEQ; s += 256) {
    float e = expf(lv[s] - mx);
    lv[s] = e;
    sm += e;
  }
#pragma unroll
  for (int off = 32; off >= 1; off >>= 1) sm += __shfl_xor(sm, off);
  if ((tid & 63) == 0) sred[tid >> 6] = sm;
  __syncthreads();
  const float inv = 1.f / (sred[0] + sred[1] + sred[2] + sred[3]);
  for (int s = tid; s < SEQ; s += 256)
    alpha[(size_t)b * SEQ + s] = lv[s] * inv;
}

// ---------------- context partials from bf16 enc copy ----------------
__global__ __launch_bounds__(256) void ctx_part_k(const unsigned short* __restrict__ encbf,
                                                  const float* __restrict__ alpha,
                                                  float* __restrict__ cpart) {
  const int blk = blockIdx.x;                   // 512 blocks
  const int b = blk & 31;
  const int ch = blk >> 5;                      // 0..15
  const int tid = threadIdx.x;
  const int g = tid >> 7;                       // 0/1 sub-chunk
  const int d0 = (tid & 127) * 8;
  const int s0 = ch * (SEQ / NCH);
  float acc8[8];
#pragma unroll
  for (int k = 0; k < 8; ++k) acc8[k] = 0.f;
#pragma unroll 4
  for (int i = 0; i < SEQ / NCH; i += 2) {
    const int s = s0 + i + g;
    const float a = alpha[(size_t)b * SEQ + s];
    u16x8 v = *reinterpret_cast<const u16x8*>(&encbf[((size_t)s * BATCH + b) * DIM + d0]);
#pragma unroll
    for (int k = 0; k < 8; ++k) {
      float f = __builtin_bit_cast(float, (unsigned)v[k] << 16);
      acc8[k] += a * f;
    }
  }
  size_t o = ((size_t)(ch * 2 + g) * BATCH + b) * DIM + d0;
  float4 lo = {acc8[0], acc8[1], acc8[2], acc8[3]};
  float4 hi = {acc8[4], acc8[5], acc8[6], acc8[7]};
  *(float4*)&cpart[o] = lo;
  *(float4*)&cpart[o + 4] = hi;
}

__global__ __launch_bounds__(256) void ctxred_k(const float* __restrict__ cpart,
                                                float* __restrict__ out) {
  int i = blockIdx.x * 256 + threadIdx.x;
  float s = 0.f;
#pragma unroll
  for (int ch = 0; ch < 32; ++ch) s += cpart[(size_t)ch * 32768 + i];
  out[i] = s;
}

extern "C" void kernel_launch(void* const* d_in, const int* in_sizes, int n_in,
                              void* d_out, int out_size, void* d_ws, size_t ws_size,
                              hipStream_t stream) {
  const float* dh   = (const float*)d_in[0];   // (32,1,1024)
  const float* enc  = (const float*)d_in[1];   // (2048,32,1024)
  const float* Wenc = (const float*)d_in[2];   // (1024,1024)
  const float* Wdec = (const float*)d_in[3];   // (1024,1024)
  const float* Vatt = (const float*)d_in[4];   // (1,1024)
  float* out = (float*)d_out;                  // [0,32768) context, [32768,98304) alpha

  float* ws = (float*)d_ws;
  float* q      = ws;                                   // 32768
  float* qpart  = ws + 32768;                           // 262144
  float* lpart  = ws + 294912;                          // 262144
  float* cpart  = ws + 557056;                          // 32*32768 = 1048576
  unsigned short* Wbf   = (unsigned short*)(ws + 1605632);  // 1Mi bf16
  unsigned short* encbf = (unsigned short*)(ws + 2129920);  // 64Mi bf16

  conv_bf16_k<<<dim3(512),   dim3(256), 0, stream>>>(Wenc, Wbf);
  qpart_k    <<<dim3(32),    dim3(256), 0, stream>>>(dh, Wdec, qpart);
  qred_k     <<<dim3(128),   dim3(256), 0, stream>>>(qpart, q);
  conv_bf16_k<<<dim3(32768), dim3(256), 0, stream>>>(enc, encbf);
  gemm8p     <<<dim3(1024),  dim3(512), 0, stream>>>(encbf, Wbf, q, Vatt, lpart);
  softmax_k  <<<dim3(BATCH),     dim3(256), 0, stream>>>(lpart, out + 32768);
  ctx_part_k <<<dim3(BATCH*NCH), dim3(256), 0, stream>>>(encbf, out + 32768, cpart);
  ctxred_k   <<<dim3(128),       dim3(256), 0, stream>>>(cpart, out);
}

// Round 14
// 268.120 us; speedup vs baseline: 4.8575x; 1.0477x over previous
//
#include <hip/hip_runtime.h>
#include <hip/hip_bf16.h>
#include <math.h>

#define SEQ   2048
#define BATCH 32
#define DIM   1024
#define MROWS (SEQ*BATCH)   // 65536 rows, r = s*32 + b
#define NT2   4             // 1024 / 256 N-tiles
#define NCH   16            // context s-chunks (x2 sub-chunks inside kernel)
#define NKT   16            // K-tiles of 64

typedef __attribute__((ext_vector_type(8))) short short8;
typedef __attribute__((ext_vector_type(8))) unsigned short u16x8;
typedef __attribute__((ext_vector_type(4))) float f32x4;

__device__ __forceinline__ unsigned short f2bf(float f) {
  unsigned u = __builtin_bit_cast(unsigned, f);
  u += 0x7FFFu + ((u >> 16) & 1u);      // round-to-nearest-even
  return (unsigned short)(u >> 16);
}

// async global -> LDS, 16 B per lane (dest = wave-uniform base + lane*16)
__device__ __forceinline__ void gl16(const unsigned short* g, unsigned short* l) {
  __builtin_amdgcn_global_load_lds(
      (const __attribute__((address_space(1))) unsigned int*)g,
      (__attribute__((address_space(3))) unsigned int*)l, 16, 0, 0);
}

// ---------------- fp32 -> bf16 bulk convert ----------------
__global__ __launch_bounds__(256) void conv_bf16_k(const float* __restrict__ src,
                                                   unsigned short* __restrict__ dst) {
  size_t i = ((size_t)blockIdx.x * 256 + threadIdx.x) * 8;
  f32x4 a = __builtin_nontemporal_load(reinterpret_cast<const f32x4*>(src + i));
  f32x4 b = __builtin_nontemporal_load(reinterpret_cast<const f32x4*>(src + i + 4));
  u16x8 o;
  o[0] = f2bf(a[0]); o[1] = f2bf(a[1]); o[2] = f2bf(a[2]); o[3] = f2bf(a[3]);
  o[4] = f2bf(b[0]); o[5] = f2bf(b[1]); o[6] = f2bf(b[2]); o[7] = f2bf(b[3]);
  *reinterpret_cast<u16x8*>(dst + i) = o;
}

// ---------------- q[b,e] = sum_d dh[b,d] * W_dec[e,d] ----------------
__global__ __launch_bounds__(256) void qpart_k(const float* __restrict__ dh,
                                               const float* __restrict__ Wd,
                                               float* __restrict__ qpart) {
  const int bx = blockIdx.x;        // 32 blocks
  const int eb = bx & 3;            // 4 e-blocks of 256
  const int dc = bx >> 2;           // 8 d-chunks of 128
  __shared__ float ldh[BATCH][128];
  const int tid = threadIdx.x;
#pragma unroll
  for (int i = 0; i < 4; ++i) {
    int idx = tid + i * 256;
    int bb = idx >> 5, d4 = idx & 31;
    float4 v = *reinterpret_cast<const float4*>(&dh[(size_t)bb * DIM + dc * 128 + d4 * 4]);
    *reinterpret_cast<float4*>(&ldh[bb][d4 * 4]) = v;
  }
  __syncthreads();
  const int e = eb * 256 + tid;
  float acc[BATCH];
#pragma unroll
  for (int b = 0; b < BATCH; ++b) acc[b] = 0.f;
  for (int d4 = 0; d4 < 32; ++d4) {
    float4 w = *reinterpret_cast<const float4*>(&Wd[(size_t)e * DIM + dc * 128 + d4 * 4]);
#pragma unroll
    for (int b = 0; b < BATCH; ++b) {
      float4 h = *reinterpret_cast<const float4*>(&ldh[b][d4 * 4]);
      acc[b] += w.x * h.x + w.y * h.y + w.z * h.z + w.w * h.w;
    }
  }
#pragma unroll
  for (int b = 0; b < BATCH; ++b)
    qpart[((size_t)dc * BATCH + b) * DIM + e] = acc[b];
}

__global__ __launch_bounds__(256) void qred_k(const float* __restrict__ qpart,
                                              float* __restrict__ q) {
  int i = blockIdx.x * 256 + threadIdx.x;
  float s = 0.f;
#pragma unroll
  for (int dc = 0; dc < 8; ++dc) s += qpart[(size_t)dc * 32768 + i];
  q[i] = s;
}

// ============ 256^2 fused GEMM: 16 waves (1024 thr), 4M x 4N, acc 64/lane ============
// Per-wave out 64x64: acc[4][4] (64 regs) -> total ~115 VGPR -> 4 waves/SIMD ->
// 16 resident waves/CU (2x the 8-wave version). LDS 128KB, BK=64, pieces =
// contiguous 128-row halves; wave reads only piece (wr>>1)/(wc>>1).
// 4 phases per 2 K-tiles; per phase: 8 ds_reads (consumed same-phase, R9-safe),
// 2 gl16 stages, BARR, 16 MFMA, BARR. vmcnt FIFO (1 gl16/thread/piece-stage):
// P1: +( t+1.h1 A,B ); P2: +(t+2.h0), VMC(2) drains t+1; P3: +(t+2.h1);
// P4: +(t+3.h0), VMC(2) drains t+2. Prologue 6 issues, VMC(2) -> t0 resident.
// Last iter: P2 -> VMC(0); P3/P4 stages suppressed. WAR: every stage >=1
// barrier after its region's reads were consumed.
#define BARR  __builtin_amdgcn_s_barrier()
#define VMC(n) asm volatile("s_waitcnt vmcnt(" #n ")" ::: "memory")

#define STAGE_A(t, h) do {                                                        \
    gl16(Abase + (size_t)(lr0 + (h) * 128) * 1024 + (t) * 64 + cSt * 8,           \
         (unsigned short*)(arena + (((t) & 1) * 65536) + (h) * 16384) + w * 512); \
  } while (0)

#define STAGE_B(t, h) do {                                                        \
    gl16(Bbase + (size_t)(lr0 + (h) * 128) * 1024 + (t) * 64 + cSt * 8,           \
         (unsigned short*)(arena + (((t) & 1) * 65536) + 32768 + (h) * 16384)     \
             + w * 512);                                                          \
  } while (0)

#define LOAD_A(d, ks) do {                                                        \
    const char* bA_ = arena + (d) * 65536 + (wr >> 1) * 16384;                    \
    _Pragma("unroll") for (int i_ = 0; i_ < 4; ++i_) {                            \
      int row_ = (wr & 1) * 64 + i_ * 16 + fr;                                    \
      int lc_ = ((ks) * 4 + kq) ^ (fr & 7);                                       \
      a[i_] = *(const short8*)(bA_ + row_ * 128 + lc_ * 16);                      \
    } } while (0)

#define LOAD_B(d, ks) do {                                                        \
    const char* bB_ = arena + (d) * 65536 + 32768 + (wc >> 1) * 16384;            \
    _Pragma("unroll") for (int j_ = 0; j_ < 4; ++j_) {                            \
      int row_ = (wc & 1) * 64 + j_ * 16 + fr;                                    \
      int lc_ = ((ks) * 4 + kq) ^ (fr & 7);                                       \
      b[j_] = *(const short8*)(bB_ + row_ * 128 + lc_ * 16);                      \
    } } while (0)

#define QUAD() do {                                                               \
    __builtin_amdgcn_s_setprio(1);                                                \
    _Pragma("unroll") for (int i_ = 0; i_ < 4; ++i_)                              \
    _Pragma("unroll") for (int j_ = 0; j_ < 4; ++j_)                              \
      acc[i_][j_] = __builtin_amdgcn_mfma_f32_16x16x32_bf16(                      \
          a[i_], b[j_], acc[i_][j_], 0, 0, 0);                                    \
    __builtin_amdgcn_s_setprio(0);                                                \
  } while (0)

__global__ __launch_bounds__(1024, 4) void gemm8p(const unsigned short* __restrict__ A,
                                                  const unsigned short* __restrict__ B,
                                                  const float* __restrict__ q,
                                                  const float* __restrict__ V,
                                                  float* __restrict__ lpart) {
  __shared__ __align__(16) char arena[131072];   // 2 bufs x (A 32KB | B 32KB)

  const int bid = blockIdx.x;
  const int wg = (bid & 7) * 128 + (bid >> 3);   // XCD-bijective (1024 % 8 == 0)
  const int mt = wg >> 2, nt = wg & 3;
  const int row0 = mt * 256, col0 = nt * 256;
  const int tid = threadIdx.x;
  const int lane = tid & 63, w = tid >> 6;       // 16 waves
  const int wr = w >> 2, wc = w & 3;             // 4M x 4N, each 64x64 out
  const int fr = lane & 15, kq = lane >> 4;

  // stage lane geometry: slot tid -> piece row lr0 = tid>>3 (0..127),
  // LDS chunk (tid&7) holds global chunk (tid&7)^(lr0&7)  [involution w/ read]
  const int lr0 = tid >> 3;
  const int cSt = (tid & 7) ^ (lr0 & 7);

  const unsigned short* Abase = A + (size_t)row0 * DIM;
  const unsigned short* Bbase = B + (size_t)col0 * DIM;

  f32x4 acc[4][4];
#pragma unroll
  for (int i = 0; i < 4; ++i)
#pragma unroll
    for (int j = 0; j < 4; ++j) acc[i][j] = (f32x4)(0.f);

  short8 a[4], b[4];     // current ks fragments (reloaded each phase)

  // ---- prologue: t0 fully + t1.h0; VMC(2) -> t0 resident, t1.h0 in flight ----
  STAGE_A(0, 0); STAGE_B(0, 0); STAGE_A(0, 1); STAGE_B(0, 1);
  STAGE_A(1, 0); STAGE_B(1, 0);
  VMC(2);
  BARR;

#pragma unroll 1
  for (int t2 = 0; t2 < NKT; t2 += 2) {
    const bool last = (t2 == NKT - 2);
    // P1: tile t2 (buf0), ks=0
    LOAD_A(0, 0); LOAD_B(0, 0);
    STAGE_A(t2 + 1, 1); STAGE_B(t2 + 1, 1);
    BARR; QUAD(); BARR;
    // P2: ks=1; gate buf1 (tile t2+1)
    LOAD_A(0, 1); LOAD_B(0, 1);
    if (!last) { STAGE_A(t2 + 2, 0); STAGE_B(t2 + 2, 0); VMC(2); } else { VMC(0); }
    BARR; QUAD(); BARR;
    // P3: tile t2+1 (buf1), ks=0
    LOAD_A(1, 0); LOAD_B(1, 0);
    if (!last) { STAGE_A(t2 + 2, 1); STAGE_B(t2 + 2, 1); }
    BARR; QUAD(); BARR;
    // P4: ks=1; gate next buf0 (tile t2+2)
    LOAD_A(1, 1); LOAD_B(1, 1);
    if (!last) { STAGE_A(t2 + 3, 0); STAGE_B(t2 + 3, 0); VMC(2); }
    BARR; QUAD(); BARR;
  }

  // ================= epilogue =================
  __syncthreads();                 // staging LDS dead; overlay q/V/red
  float* qld = (float*)arena;                    // [32][260] padded -> 33280 B
  float* vld = (float*)(arena + 33280);          // [256]
  float* red = (float*)(arena + 34304);          // [4][256]
#pragma unroll
  for (int i = 0; i < 2; ++i) {
    int id = i * 1024 + tid;                     // 2048 float4s
    int bb = id >> 6, e4 = id & 63;
    float4 v = *(const float4*)&q[(size_t)bb * DIM + col0 + e4 * 4];
    *(float4*)&qld[bb * 260 + e4 * 4] = v;
  }
  if (tid < 64) *(float4*)&vld[tid * 4] = *(const float4*)&V[col0 + tid * 4];
  __syncthreads();

#pragma unroll
  for (int mf = 0; mf < 4; ++mf) {
#pragma unroll
    for (int reg = 0; reg < 4; ++reg) {
      const int m_loc = wr * 64 + mf * 16 + kq * 4 + reg;
      const int bb = m_loc & 31;                 // row0 % 32 == 0
      float val = 0.f;
#pragma unroll
      for (int nf = 0; nf < 4; ++nf) {
        const int el = wc * 64 + nf * 16 + fr;
        float x = acc[mf][nf][reg] + qld[bb * 260 + el];
        float g = __expf(2.f * x);
        float tnh = 1.f - 2.f * __builtin_amdgcn_rcpf(g + 1.f);
        val += tnh * vld[el];
      }
      val += __shfl_xor(val, 1); val += __shfl_xor(val, 2);
      val += __shfl_xor(val, 4); val += __shfl_xor(val, 8);
      if (fr == 0) red[wc * 256 + m_loc] = val;
    }
  }
  __syncthreads();
  if (tid < 256) {
    float s = red[tid] + red[256 + tid] + red[512 + tid] + red[768 + tid];
    lpart[(size_t)(row0 + tid) * NT2 + nt] = s;
  }
}

// ---------------- softmax over seq per batch ----------------
__global__ __launch_bounds__(256) void softmax_k(const float* __restrict__ lpart,
                                                 float* __restrict__ alpha) {
  const int b = blockIdx.x;
  __shared__ float lv[SEQ];
  __shared__ float sred[4];
  const int tid = threadIdx.x;
  float mx = -1e30f;
  for (int s = tid; s < SEQ; s += 256) {
    const float* p = &lpart[(size_t)(s * BATCH + b) * NT2];
    float v = p[0] + p[1] + p[2] + p[3];
    lv[s] = v;
    mx = fmaxf(mx, v);
  }
#pragma unroll
  for (int off = 32; off >= 1; off >>= 1) mx = fmaxf(mx, __shfl_xor(mx, off));
  if ((tid & 63) == 0) sred[tid >> 6] = mx;
  __syncthreads();
  mx = fmaxf(fmaxf(sred[0], sred[1]), fmaxf(sred[2], sred[3]));
  __syncthreads();
  float sm = 0.f;
  for (int s = tid; s < SEQ; s += 256) {
    float e = expf(lv[s] - mx);
    lv[s] = e;
    sm += e;
  }
#pragma unroll
  for (int off = 32; off >= 1; off >>= 1) sm += __shfl_xor(sm, off);
  if ((tid & 63) == 0) sred[tid >> 6] = sm;
  __syncthreads();
  const float inv = 1.f / (sred[0] + sred[1] + sred[2] + sred[3]);
  for (int s = tid; s < SEQ; s += 256)
    alpha[(size_t)b * SEQ + s] = lv[s] * inv;
}

// ---------------- context partials from bf16 enc copy ----------------
__global__ __launch_bounds__(256) void ctx_part_k(const unsigned short* __restrict__ encbf,
                                                  const float* __restrict__ alpha,
                                                  float* __restrict__ cpart) {
  const int blk = blockIdx.x;                   // 512 blocks
  const int b = blk & 31;
  const int ch = blk >> 5;                      // 0..15
  const int tid = threadIdx.x;
  const int g = tid >> 7;                       // 0/1 sub-chunk
  const int d0 = (tid & 127) * 8;
  const int s0 = ch * (SEQ / NCH);
  float acc8[8];
#pragma unroll
  for (int k = 0; k < 8; ++k) acc8[k] = 0.f;
#pragma unroll 4
  for (int i = 0; i < SEQ / NCH; i += 2) {
    const int s = s0 + i + g;
    const float a = alpha[(size_t)b * SEQ + s];
    u16x8 v = *reinterpret_cast<const u16x8*>(&encbf[((size_t)s * BATCH + b) * DIM + d0]);
#pragma unroll
    for (int k = 0; k < 8; ++k) {
      float f = __builtin_bit_cast(float, (unsigned)v[k] << 16);
      acc8[k] += a * f;
    }
  }
  size_t o = ((size_t)(ch * 2 + g) * BATCH + b) * DIM + d0;
  float4 lo = {acc8[0], acc8[1], acc8[2], acc8[3]};
  float4 hi = {acc8[4], acc8[5], acc8[6], acc8[7]};
  *(float4*)&cpart[o] = lo;
  *(float4*)&cpart[o + 4] = hi;
}

__global__ __launch_bounds__(256) void ctxred_k(const float* __restrict__ cpart,
                                                float* __restrict__ out) {
  int i = blockIdx.x * 256 + threadIdx.x;
  float s = 0.f;
#pragma unroll
  for (int ch = 0; ch < 32; ++ch) s += cpart[(size_t)ch * 32768 + i];
  out[i] = s;
}

extern "C" void kernel_launch(void* const* d_in, const int* in_sizes, int n_in,
                              void* d_out, int out_size, void* d_ws, size_t ws_size,
                              hipStream_t stream) {
  const float* dh   = (const float*)d_in[0];   // (32,1,1024)
  const float* enc  = (const float*)d_in[1];   // (2048,32,1024)
  const float* Wenc = (const float*)d_in[2];   // (1024,1024)
  const float* Wdec = (const float*)d_in[3];   // (1024,1024)
  const float* Vatt = (const float*)d_in[4];   // (1,1024)
  float* out = (float*)d_out;                  // [0,32768) context, [32768,98304) alpha

  float* ws = (float*)d_ws;
  float* q      = ws;                                   // 32768
  float* qpart  = ws + 32768;                           // 262144
  float* lpart  = ws + 294912;                          // 262144
  float* cpart  = ws + 557056;                          // 32*32768 = 1048576
  unsigned short* Wbf   = (unsigned short*)(ws + 1605632);  // 1Mi bf16
  unsigned short* encbf = (unsigned short*)(ws + 2129920);  // 64Mi bf16

  conv_bf16_k<<<dim3(512),   dim3(256), 0, stream>>>(Wenc, Wbf);
  qpart_k    <<<dim3(32),    dim3(256), 0, stream>>>(dh, Wdec, qpart);
  qred_k     <<<dim3(128),   dim3(256), 0, stream>>>(qpart, q);
  conv_bf16_k<<<dim3(32768), dim3(256), 0, stream>>>(enc, encbf);
  gemm8p     <<<dim3(1024),  dim3(1024), 0, stream>>>(encbf, Wbf, q, Vatt, lpart);
  softmax_k  <<<dim3(BATCH),     dim3(256), 0, stream>>>(lpart, out + 32768);
  ctx_part_k <<<dim3(BATCH*NCH), dim3(256), 0, stream>>>(encbf, out + 32768, cpart);
  ctxred_k   <<<dim3(128),       dim3(256), 0, stream>>>(cpart, out);
}